// Round 1
// baseline (35060.196 us; speedup 1.0000x reference)
//
#include <hip/hip_runtime.h>
#include <stdint.h>

#define STEPS 100
#define BATCH 512

// ---------------------------------------------------------------------------
// Threefry2x32 (JAX-exact, 20 rounds)
// ---------------------------------------------------------------------------
__device__ __forceinline__ uint32_t rotl32(uint32_t v, int r) {
  return (v << r) | (v >> (32 - r));
}

__device__ __forceinline__ void tf2x32(uint32_t k0, uint32_t k1,
                                       uint32_t x0, uint32_t x1,
                                       uint32_t& o0, uint32_t& o1) {
  uint32_t ks2 = k0 ^ k1 ^ 0x1BD11BDAu;
  x0 += k0; x1 += k1;
#define RND(r) { x0 += x1; x1 = rotl32(x1, (r)); x1 ^= x0; }
  RND(13) RND(15) RND(26) RND(6)
  x0 += k1;  x1 += ks2 + 1u;
  RND(17) RND(29) RND(16) RND(24)
  x0 += ks2; x1 += k0 + 2u;
  RND(13) RND(15) RND(26) RND(6)
  x0 += k0;  x1 += k1 + 3u;
  RND(17) RND(29) RND(16) RND(24)
  x0 += k1;  x1 += ks2 + 4u;
  RND(13) RND(15) RND(26) RND(6)
  x0 += ks2; x1 += k0 + 5u;
#undef RND
  o0 = x0; o1 = x1;
}

// keys[i] = threefry2x32((0,42), (0,i))  (fold-like split, partitionable mode)
__global__ void keys_kernel(uint32_t* __restrict__ keybuf) {
  int i = threadIdx.x;
  if (i < STEPS) {
    uint32_t a, b;
    tf2x32(0u, 42u, 0u, (uint32_t)i, a, b);
    keybuf[2 * i]     = a;
    keybuf[2 * i + 1] = b;
  }
}

// ---------------------------------------------------------------------------
// Poisson spike generation: r = uniform bits (partitionable: o0 ^ o1)
// pois[j] = (|x[j]|/2 > r) ? sign(x[j]) : 0
// ---------------------------------------------------------------------------
#define NIN 401408  // 512*1*28*28

__global__ void poisson_kernel(const float* __restrict__ x,
                               const uint32_t* __restrict__ keybuf,
                               int step, float* __restrict__ pois) {
  int j = blockIdx.x * blockDim.x + threadIdx.x;
  if (j >= NIN) return;
  uint32_t k0 = keybuf[2 * step], k1 = keybuf[2 * step + 1];
  uint32_t o0, o1;
  tf2x32(k0, k1, 0u, (uint32_t)j, o0, o1);
  uint32_t bits = o0 ^ o1;
  float r = __uint_as_float((bits >> 9) | 0x3F800000u) - 1.0f;
  float xv = x[j];
  float sgn = (xv > 0.f) ? 1.f : ((xv < 0.f) ? -1.f : 0.f);
  pois[j] = (fabsf(xv) * 0.5f > r) ? sgn : 0.f;
}

// ---------------------------------------------------------------------------
// conv1 (1->20, 5x5, pad 2) + IF fire (vth=1). Block per batch sample.
// job = oc*28 + y; each thread computes one full output row (28 px).
// ---------------------------------------------------------------------------
__global__ __launch_bounds__(256) void conv1_fire(
    const float* __restrict__ pois, const float* __restrict__ w1,
    float* __restrict__ m1, float* __restrict__ s1) {
  __shared__ float in_s[28 * 32];   // rows padded to 32
  __shared__ float w_s[20 * 25];
  int b = blockIdx.x;
  const float* inb = pois + b * 784;
  for (int i = threadIdx.x; i < 784; i += 256)
    in_s[(i / 28) * 32 + (i % 28)] = inb[i];
  for (int i = threadIdx.x; i < 500; i += 256)
    w_s[i] = w1[i];
  __syncthreads();

  for (int j = threadIdx.x; j < 20 * 28; j += 256) {
    int oc = j / 28, y = j % 28;
    float acc[28];
#pragma unroll
    for (int xx = 0; xx < 28; ++xx) acc[xx] = 0.f;
    const float* wb = w_s + oc * 25;
#pragma unroll
    for (int ky = 0; ky < 5; ++ky) {
      int iy = y + ky - 2;
      if (iy < 0 || iy >= 28) continue;
      float rr[28];
#pragma unroll
      for (int ix = 0; ix < 28; ++ix) rr[ix] = in_s[iy * 32 + ix];
#pragma unroll
      for (int kx = 0; kx < 5; ++kx) {
        float w = wb[ky * 5 + kx];
#pragma unroll
        for (int xx = 0; xx < 28; ++xx) {
          int ix = xx + kx - 2;
          if (ix >= 0 && ix < 28) acc[xx] += w * rr[ix];
        }
      }
    }
    int base = (b * 20 + oc) * 784 + y * 28;
#pragma unroll
    for (int xx = 0; xx < 28; ++xx) {
      float m = m1[base + xx] + acc[xx];
      float sp = 0.f;
      if (m > 1.0f) { sp = 1.f; m = 0.f; }
      m1[base + xx] = m;
      s1[base + xx] = sp;
    }
  }
}

// ---------------------------------------------------------------------------
// 2x2 avgpool + IF fire (generic). One thread per output element.
// ---------------------------------------------------------------------------
__global__ void pool_fire(const float* __restrict__ sin, float* __restrict__ ms,
                          float* __restrict__ sout, int n, int H, float th) {
  int idx = blockIdx.x * blockDim.x + threadIdx.x;
  if (idx >= n) return;
  int Ho = H >> 1;
  int pp = Ho * Ho;
  int p = idx % pp;
  int t = idx / pp;
  int y = p / Ho, x = p % Ho;
  const float* base = sin + t * H * H + (2 * y) * H + 2 * x;
  float a = 0.25f * (base[0] + base[1] + base[H] + base[H + 1]);
  float m = ms[idx] + a;
  float sp = 0.f;
  if (m > th) { sp = 1.f; m = 0.f; }
  ms[idx] = m;
  sout[idx] = sp;
}

// ---------------------------------------------------------------------------
// conv2 (20->50, 5x5, pad 2, 14x14) + IF fire. Block per batch sample.
// job = oc*14 + y; thread computes one full output row (14 px).
// ---------------------------------------------------------------------------
__global__ __launch_bounds__(256) void conv2_fire(
    const float* __restrict__ sp1, const float* __restrict__ w2,
    float* __restrict__ m2, float* __restrict__ s2) {
  __shared__ float in_s[20 * 14 * 16];  // [ic][iy][ix padded to 16]
  int b = blockIdx.x;
  const float* inb = sp1 + b * 3920;
  for (int i = threadIdx.x; i < 3920; i += 256) {
    int ic = i / 196, r = i % 196;
    in_s[ic * 224 + (r / 14) * 16 + (r % 14)] = inb[i];
  }
  __syncthreads();

  for (int j = threadIdx.x; j < 50 * 14; j += 256) {
    int oc = j / 14, y = j % 14;
    float acc[14];
#pragma unroll
    for (int xx = 0; xx < 14; ++xx) acc[xx] = 0.f;
    const float* wb = w2 + oc * 500;
    for (int ic = 0; ic < 20; ++ic) {
      const float* ins = in_s + ic * 224;
      const float* wc = wb + ic * 25;
#pragma unroll
      for (int ky = 0; ky < 5; ++ky) {
        int iy = y + ky - 2;
        if (iy < 0 || iy >= 14) continue;
        float rr[14];
#pragma unroll
        for (int ix = 0; ix < 14; ++ix) rr[ix] = ins[iy * 16 + ix];
#pragma unroll
        for (int kx = 0; kx < 5; ++kx) {
          float w = wc[ky * 5 + kx];
#pragma unroll
          for (int xx = 0; xx < 14; ++xx) {
            int ix = xx + kx - 2;
            if (ix >= 0 && ix < 14) acc[xx] += w * rr[ix];
          }
        }
      }
    }
    int base = (b * 50 + oc) * 196 + y * 14;
#pragma unroll
    for (int xx = 0; xx < 14; ++xx) {
      float m = m2[base + xx] + acc[xx];
      float sp = 0.f;
      if (m > 1.0f) { sp = 1.f; m = 0.f; }
      m2[base + xx] = m;
      s2[base + xx] = sp;
    }
  }
}

// ---------------------------------------------------------------------------
// wf0 transpose: wf0T[k*200+n] = wf0[n*2450+k]
// ---------------------------------------------------------------------------
__global__ void transpose_wf0(const float* __restrict__ wf0,
                              float* __restrict__ wf0T) {
  int idx = blockIdx.x * blockDim.x + threadIdx.x;
  if (idx >= 200 * 2450) return;
  int n = idx / 2450, k = idx % 2450;
  wf0T[k * 200 + n] = wf0[idx];
}

// ---------------------------------------------------------------------------
// fc0 (2450->200) + IF fire + Tf0 accumulate. 2 batch samples per thread.
// ---------------------------------------------------------------------------
__global__ __launch_bounds__(256) void fc0_fire(
    const float* __restrict__ sp2, const float* __restrict__ wf0T,
    float* __restrict__ mf0, float* __restrict__ Tf0) {
  int idx = blockIdx.x * blockDim.x + threadIdx.x;
  if (idx >= 256 * 200) return;
  int n = idx % 200;
  int b0 = (idx / 200) * 2;
  const float* sA = sp2 + b0 * 2450;
  const float* sB = sA + 2450;
  float a0 = 0.f, a1 = 0.f;
  for (int k = 0; k < 2450; ++k) {
    float w = wf0T[k * 200 + n];
    a0 += sA[k] * w;
    a1 += sB[k] * w;
  }
  int i0 = b0 * 200 + n, i1 = i0 + 200;
  float m0 = mf0[i0] + a0;
  float s0 = 0.f;
  if (m0 > 1.0f) { s0 = 1.f; m0 = 0.f; }
  mf0[i0] = m0; Tf0[i0] += s0;
  float m1 = mf0[i1] + a1;
  float s1 = 0.f;
  if (m1 > 1.0f) { s1 = 1.f; m1 = 0.f; }
  mf0[i1] = m1; Tf0[i1] += s1;
}

// ---------------------------------------------------------------------------
// final: out[b][i] = (Tf0[b] . wf1[i]) / VTH / STEPS
// ---------------------------------------------------------------------------
__global__ void fc1_out(const float* __restrict__ Tf0,
                        const float* __restrict__ wf1,
                        float* __restrict__ out) {
  int idx = blockIdx.x * blockDim.x + threadIdx.x;
  if (idx >= BATCH * 10) return;
  int b = idx / 10, i = idx % 10;
  float a = 0.f;
  for (int j = 0; j < 200; ++j) a += Tf0[b * 200 + j] * wf1[i * 200 + j];
  out[idx] = (a / 1.0f) / 100.0f;
}

// ---------------------------------------------------------------------------
extern "C" void kernel_launch(void* const* d_in, const int* in_sizes, int n_in,
                              void* d_out, int out_size, void* d_ws, size_t ws_size,
                              hipStream_t stream) {
  (void)in_sizes; (void)n_in; (void)out_size; (void)ws_size;
  const float* x   = (const float*)d_in[0];
  const float* w1  = (const float*)d_in[1];
  const float* w2  = (const float*)d_in[2];
  const float* wf0 = (const float*)d_in[3];
  const float* wf1 = (const float*)d_in[4];
  float* out = (float*)d_out;
  float* ws  = (float*)d_ws;

  // workspace layout (floats)
  float* m1   = ws;                 // 512*20*784  = 8,028,160
  float* m1s  = m1   + 8028160;     // 512*20*196  = 2,007,040
  float* m2   = m1s  + 2007040;     // 512*50*196  = 5,017,600
  float* m2s  = m2   + 5017600;     // 512*50*49   = 1,254,400
  float* mf0  = m2s  + 1254400;     // 512*200     =   102,400
  float* Tf0  = mf0  + 102400;      //             =   102,400
  const size_t state_f = 8028160 + 2007040 + 5017600 + 1254400 + 102400 + 102400;
  float* pois = Tf0  + 102400;      // 401,408
  float* s1   = pois + 401408;      // 8,028,160
  float* sp1  = s1   + 8028160;     // 2,007,040
  float* s2   = sp1  + 2007040;     // 5,017,600
  float* sp2  = s2   + 5017600;     // 1,254,400
  float* wf0T = sp2  + 1254400;     // 490,000
  uint32_t* keybuf = (uint32_t*)(wf0T + 490000);  // 200 u32

  // zero all membranes + Tf0 (ws is poisoned before every launch)
  hipMemsetAsync(ws, 0, state_f * sizeof(float), stream);

  keys_kernel<<<1, 128, 0, stream>>>(keybuf);
  transpose_wf0<<<(200 * 2450 + 255) / 256, 256, 0, stream>>>(wf0, wf0T);

  for (int s = 0; s < STEPS; ++s) {
    poisson_kernel<<<(NIN + 255) / 256, 256, 0, stream>>>(x, keybuf, s, pois);
    conv1_fire<<<BATCH, 256, 0, stream>>>(pois, w1, m1, s1);
    pool_fire<<<(2007040 + 255) / 256, 256, 0, stream>>>(s1, m1s, sp1,
                                                         2007040, 28, 0.75f);
    conv2_fire<<<BATCH, 256, 0, stream>>>(sp1, w2, m2, s2);
    pool_fire<<<(1254400 + 255) / 256, 256, 0, stream>>>(s2, m2s, sp2,
                                                         1254400, 14, 0.75f);
    fc0_fire<<<(256 * 200 + 255) / 256, 256, 0, stream>>>(sp2, wf0T, mf0, Tf0);
  }
  fc1_out<<<(BATCH * 10 + 255) / 256, 256, 0, stream>>>(Tf0, wf1, out);
}

// Round 2
// 31134.137 us; speedup vs baseline: 1.1261x; 1.1261x over previous
//
#include <hip/hip_runtime.h>
#include <stdint.h>

#define STEPS 100
#define BATCH 512

// ---------------------------------------------------------------------------
// Threefry2x32 (JAX-exact, 20 rounds)
// ---------------------------------------------------------------------------
__device__ __forceinline__ uint32_t rotl32(uint32_t v, int r) {
  return (v << r) | (v >> (32 - r));
}

__device__ __forceinline__ void tf2x32(uint32_t k0, uint32_t k1,
                                       uint32_t x0, uint32_t x1,
                                       uint32_t& o0, uint32_t& o1) {
  uint32_t ks2 = k0 ^ k1 ^ 0x1BD11BDAu;
  x0 += k0; x1 += k1;
#define RND(r) { x0 += x1; x1 = rotl32(x1, (r)); x1 ^= x0; }
  RND(13) RND(15) RND(26) RND(6)
  x0 += k1;  x1 += ks2 + 1u;
  RND(17) RND(29) RND(16) RND(24)
  x0 += ks2; x1 += k0 + 2u;
  RND(13) RND(15) RND(26) RND(6)
  x0 += k0;  x1 += k1 + 3u;
  RND(17) RND(29) RND(16) RND(24)
  x0 += k1;  x1 += ks2 + 4u;
  RND(13) RND(15) RND(26) RND(6)
  x0 += ks2; x1 += k0 + 5u;
#undef RND
  o0 = x0; o1 = x1;
}

__global__ void keys_kernel(uint32_t* __restrict__ keybuf) {
  int i = threadIdx.x;
  if (i < STEPS) {
    uint32_t a, b;
    tf2x32(0u, 42u, 0u, (uint32_t)i, a, b);
    keybuf[2 * i]     = a;
    keybuf[2 * i + 1] = b;
  }
}

// ---------------------------------------------------------------------------
// Poisson spikes, batch-innermost output: pois_t[p*512 + b], p = pixel 0..783
// JAX element index j = b*784 + p (must feed threefry with j).
// ---------------------------------------------------------------------------
#define NIN 401408  // 512*784

__global__ void poisson_t(const float* __restrict__ x,
                          const uint32_t* __restrict__ keybuf,
                          int step, float* __restrict__ pois_t) {
  int t = blockIdx.x * blockDim.x + threadIdx.x;
  if (t >= NIN) return;
  int p = t >> 9;
  int b = t & 511;
  int j = b * 784 + p;
  uint32_t k0 = keybuf[2 * step], k1 = keybuf[2 * step + 1];
  uint32_t o0, o1;
  tf2x32(k0, k1, 0u, (uint32_t)j, o0, o1);
  uint32_t bits = o0 ^ o1;
  float r = __uint_as_float((bits >> 9) | 0x3F800000u) - 1.0f;
  float xv = x[j];
  float sgn = (xv > 0.f) ? 1.f : ((xv < 0.f) ? -1.f : 0.f);
  pois_t[t] = (fabsf(xv) * 0.5f > r) ? sgn : 0.f;
}

// ---------------------------------------------------------------------------
// conv1 (1->20, 5x5, pad 2, 28x28) + IF fire. Lane = batch.
// Block = (pixel p, 256-batch half). acc[20] in regs; weights via s_load.
// Sum order per output: (ky,kx) ascending — bitwise identical to round 1.
// ---------------------------------------------------------------------------
__global__ __launch_bounds__(256) void conv1_fire_t(
    const float* __restrict__ pois_t, const float* __restrict__ w1,
    float* __restrict__ m1, float* __restrict__ s1) {
  int p = blockIdx.x >> 1;
  int b = ((blockIdx.x & 1) << 8) + threadIdx.x;
  int y = p / 28, x = p % 28;
  float acc[20];
#pragma unroll
  for (int oc = 0; oc < 20; ++oc) acc[oc] = 0.f;
#pragma unroll
  for (int ky = 0; ky < 5; ++ky) {
    int iy = y + ky - 2;
    if (iy < 0 || iy >= 28) continue;       // block-uniform branch
#pragma unroll
    for (int kx = 0; kx < 5; ++kx) {
      int ix = x + kx - 2;
      if (ix < 0 || ix >= 28) continue;     // block-uniform branch
      float v = pois_t[(iy * 28 + ix) * 512 + b];
#pragma unroll
      for (int oc = 0; oc < 20; ++oc)
        acc[oc] += w1[oc * 25 + ky * 5 + kx] * v;
    }
  }
#pragma unroll
  for (int oc = 0; oc < 20; ++oc) {
    int idx = (oc * 784 + p) * 512 + b;
    float m = m1[idx] + acc[oc];
    float sp = 0.f;
    if (m > 1.0f) { sp = 1.f; m = 0.f; }
    m1[idx] = m;
    s1[idx] = sp;
  }
}

// ---------------------------------------------------------------------------
// 2x2 avgpool + IF fire, batch-innermost. One thread per output element.
// ---------------------------------------------------------------------------
__global__ void pool_fire_t(const float* __restrict__ sin,
                            float* __restrict__ ms, float* __restrict__ sout,
                            int n, int H, float th) {
  int t = blockIdx.x * blockDim.x + threadIdx.x;
  if (t >= n) return;
  int b = t & 511;
  int r = t >> 9;
  int Ho = H >> 1;
  int pp = Ho * Ho;
  int c = r / pp, q = r % pp;
  int yo = q / Ho, xo = q % Ho;
  int ibase = (c * H * H + 2 * yo * H + 2 * xo) * 512 + b;
  float a = 0.25f * (sin[ibase] + sin[ibase + 512] +
                     sin[ibase + H * 512] + sin[ibase + H * 512 + 512]);
  float m = ms[t] + a;
  float sp = 0.f;
  if (m > th) { sp = 1.f; m = 0.f; }
  ms[t] = m;
  sout[t] = sp;
}

// ---------------------------------------------------------------------------
// w2 transpose: wT[q*50 + oc] = w2[oc*500 + q], q = ic*25 + ky*5 + kx
// ---------------------------------------------------------------------------
__global__ void transpose_w2(const float* __restrict__ w2,
                             float* __restrict__ wT) {
  int i = blockIdx.x * blockDim.x + threadIdx.x;
  if (i >= 25000) return;
  int oc = i / 500, q = i % 500;
  wT[q * 50 + oc] = w2[i];
}

// ---------------------------------------------------------------------------
// conv2 (20->50, 5x5, pad 2, 14x14) + IF fire. Lane = batch, acc[50] in regs.
// Weights from wT: 50 consecutive floats per tap -> s_load_dwordx16 clusters.
// Sum order per output: (ic,ky,kx) ascending — bitwise identical to round 1.
// ---------------------------------------------------------------------------
__global__ __launch_bounds__(256) void conv2_fire_t(
    const float* __restrict__ sp1, const float* __restrict__ wT,
    float* __restrict__ m2, float* __restrict__ s2) {
  int p = blockIdx.x >> 1;
  int b = ((blockIdx.x & 1) << 8) + threadIdx.x;
  int y = p / 14, x = p % 14;
  float acc[50];
#pragma unroll
  for (int oc = 0; oc < 50; ++oc) acc[oc] = 0.f;
  for (int ic = 0; ic < 20; ++ic) {
#pragma unroll
    for (int ky = 0; ky < 5; ++ky) {
      int iy = y + ky - 2;
      if (iy < 0 || iy >= 14) continue;     // block-uniform
#pragma unroll
      for (int kx = 0; kx < 5; ++kx) {
        int ix = x + kx - 2;
        if (ix < 0 || ix >= 14) continue;   // block-uniform
        float v = sp1[(ic * 196 + iy * 14 + ix) * 512 + b];
        const float* wrow = wT + (ic * 25 + ky * 5 + kx) * 50;
#pragma unroll
        for (int oc = 0; oc < 50; ++oc)
          acc[oc] += wrow[oc] * v;
      }
    }
  }
#pragma unroll
  for (int oc = 0; oc < 50; ++oc) {
    int idx = (oc * 196 + p) * 512 + b;
    float m = m2[idx] + acc[oc];
    float sp = 0.f;
    if (m > 1.0f) { sp = 1.f; m = 0.f; }
    m2[idx] = m;
    s2[idx] = sp;
  }
}

// ---------------------------------------------------------------------------
// fc0 (2450->200) + IF fire + Tf0 accumulate. Lane = batch; thread owns 4 n.
// k ascending — bitwise identical to round 1. Weights wf0[n][k] via s_load.
// ---------------------------------------------------------------------------
__global__ __launch_bounds__(256) void fc0_fire_t(
    const float* __restrict__ sp2, const float* __restrict__ wf0,
    float* __restrict__ mf0, float* __restrict__ Tf0) {
  int t = blockIdx.x * blockDim.x + threadIdx.x;  // 50*512 threads
  int b = t & 511;
  int g = t >> 9;      // 0..49
  int n0 = g * 4;
  float acc[4] = {0.f, 0.f, 0.f, 0.f};
  const float* w0 = wf0 + n0 * 2450;
  for (int k = 0; k < 2450; ++k) {
    float v = sp2[k * 512 + b];
#pragma unroll
    for (int i = 0; i < 4; ++i)
      acc[i] += w0[i * 2450 + k] * v;
  }
#pragma unroll
  for (int i = 0; i < 4; ++i) {
    int idx = (n0 + i) * 512 + b;
    float m = mf0[idx] + acc[i];
    float sp = 0.f;
    if (m > 1.0f) { sp = 1.f; m = 0.f; }
    mf0[idx] = m;
    Tf0[idx] += sp;
  }
}

// ---------------------------------------------------------------------------
// final: out[b][i] = (Tf0_t[.][b] . wf1[i]) / 1 / 100
// ---------------------------------------------------------------------------
__global__ void fc1_out_t(const float* __restrict__ Tf0,
                          const float* __restrict__ wf1,
                          float* __restrict__ out) {
  int idx = blockIdx.x * blockDim.x + threadIdx.x;
  if (idx >= BATCH * 10) return;
  int b = idx / 10, i = idx % 10;
  float a = 0.f;
  for (int j = 0; j < 200; ++j) a += Tf0[j * 512 + b] * wf1[i * 200 + j];
  out[idx] = (a / 1.0f) / 100.0f;
}

// ---------------------------------------------------------------------------
extern "C" void kernel_launch(void* const* d_in, const int* in_sizes, int n_in,
                              void* d_out, int out_size, void* d_ws, size_t ws_size,
                              hipStream_t stream) {
  (void)in_sizes; (void)n_in; (void)out_size; (void)ws_size;
  const float* x   = (const float*)d_in[0];
  const float* w1  = (const float*)d_in[1];
  const float* w2  = (const float*)d_in[2];
  const float* wf0 = (const float*)d_in[3];
  const float* wf1 = (const float*)d_in[4];
  float* out = (float*)d_out;
  float* ws  = (float*)d_ws;

  // state (zeroed once per launch), all batch-innermost
  float* m1   = ws;                 // [20*784][512]  = 8,028,160
  float* m1s  = m1   + 8028160;     // [20*196][512]  = 2,007,040
  float* m2   = m1s  + 2007040;     // [50*196][512]  = 5,017,600
  float* m2s  = m2   + 5017600;     // [50*49][512]   = 1,254,400
  float* mf0  = m2s  + 1254400;     // [200][512]     =   102,400
  float* Tf0  = mf0  + 102400;      //                =   102,400
  const size_t state_f = 8028160 + 2007040 + 5017600 + 1254400 + 102400 + 102400;
  // transients
  float* pois = Tf0  + 102400;      // [784][512]     =   401,408
  float* s1   = pois + 401408;      // [20*784][512]  = 8,028,160
  float* sp1  = s1   + 8028160;     // [20*196][512]  = 2,007,040
  float* s2   = sp1  + 2007040;     // [50*196][512]  = 5,017,600
  float* sp2  = s2   + 5017600;     // [50*49][512]   = 1,254,400
  float* wT   = sp2  + 1254400;     // [500][50]      =    25,000
  uint32_t* keybuf = (uint32_t*)(wT + 25000);  // 200 u32

  hipMemsetAsync(ws, 0, state_f * sizeof(float), stream);

  keys_kernel<<<1, 128, 0, stream>>>(keybuf);
  transpose_w2<<<(25000 + 255) / 256, 256, 0, stream>>>(w2, wT);

  for (int s = 0; s < STEPS; ++s) {
    poisson_t<<<(NIN + 255) / 256, 256, 0, stream>>>(x, keybuf, s, pois);
    conv1_fire_t<<<784 * 2, 256, 0, stream>>>(pois, w1, m1, s1);
    pool_fire_t<<<(2007040 + 255) / 256, 256, 0, stream>>>(s1, m1s, sp1,
                                                           2007040, 28, 0.75f);
    conv2_fire_t<<<196 * 2, 256, 0, stream>>>(sp1, wT, m2, s2);
    pool_fire_t<<<(1254400 + 255) / 256, 256, 0, stream>>>(s2, m2s, sp2,
                                                           1254400, 14, 0.75f);
    fc0_fire_t<<<(50 * 512 + 255) / 256, 256, 0, stream>>>(sp2, wf0, mf0, Tf0);
  }
  fc1_out_t<<<(BATCH * 10 + 255) / 256, 256, 0, stream>>>(Tf0, wf1, out);
}

// Round 3
// 27103.427 us; speedup vs baseline: 1.2936x; 1.1487x over previous
//
#include <hip/hip_runtime.h>
#include <stdint.h>

#define STEPS 100
#define BATCH 512

// ---------------------------------------------------------------------------
// Threefry2x32 (JAX-exact, 20 rounds)
// ---------------------------------------------------------------------------
__device__ __forceinline__ uint32_t rotl32(uint32_t v, int r) {
  return (v << r) | (v >> (32 - r));
}

__device__ __forceinline__ void tf2x32(uint32_t k0, uint32_t k1,
                                       uint32_t x0, uint32_t x1,
                                       uint32_t& o0, uint32_t& o1) {
  uint32_t ks2 = k0 ^ k1 ^ 0x1BD11BDAu;
  x0 += k0; x1 += k1;
#define RND(r) { x0 += x1; x1 = rotl32(x1, (r)); x1 ^= x0; }
  RND(13) RND(15) RND(26) RND(6)
  x0 += k1;  x1 += ks2 + 1u;
  RND(17) RND(29) RND(16) RND(24)
  x0 += ks2; x1 += k0 + 2u;
  RND(13) RND(15) RND(26) RND(6)
  x0 += k0;  x1 += k1 + 3u;
  RND(17) RND(29) RND(16) RND(24)
  x0 += k1;  x1 += ks2 + 4u;
  RND(13) RND(15) RND(26) RND(6)
  x0 += ks2; x1 += k0 + 5u;
#undef RND
  o0 = x0; o1 = x1;
}

__global__ void keys_kernel(uint32_t* __restrict__ keybuf) {
  int i = threadIdx.x;
  if (i < STEPS) {
    uint32_t a, b;
    tf2x32(0u, 42u, 0u, (uint32_t)i, a, b);
    keybuf[2 * i]     = a;
    keybuf[2 * i + 1] = b;
  }
}

// ---------------------------------------------------------------------------
// Poisson spikes, batch-innermost: pois_t[p*512 + b]; JAX index j = b*784 + p
// ---------------------------------------------------------------------------
#define NIN 401408  // 512*784

__global__ void poisson_t(const float* __restrict__ x,
                          const uint32_t* __restrict__ keybuf,
                          int step, float* __restrict__ pois_t) {
  int t = blockIdx.x * blockDim.x + threadIdx.x;
  if (t >= NIN) return;
  int p = t >> 9;
  int b = t & 511;
  int j = b * 784 + p;
  uint32_t k0 = keybuf[2 * step], k1 = keybuf[2 * step + 1];
  uint32_t o0, o1;
  tf2x32(k0, k1, 0u, (uint32_t)j, o0, o1);
  uint32_t bits = o0 ^ o1;
  float r = __uint_as_float((bits >> 9) | 0x3F800000u) - 1.0f;
  float xv = x[j];
  float sgn = (xv > 0.f) ? 1.f : ((xv < 0.f) ? -1.f : 0.f);
  pois_t[t] = (fabsf(xv) * 0.5f > r) ? sgn : 0.f;
}

// ---------------------------------------------------------------------------
// Fused conv1 (1->20, 5x5, pad 2) + IF fire + 2x2 avgpool + IF fire.
// Block = (pool-quad q, 256-batch half); lane = batch.
// Conv sum order (ky,kx), pool order ((s00+s01)+s10)+s11 — bitwise identical
// to the unfused round-2 kernels.
// ---------------------------------------------------------------------------
__global__ __launch_bounds__(256) void conv1_pool1_fused(
    const float* __restrict__ pois_t, const float* __restrict__ w1,
    float* __restrict__ m1, float* __restrict__ m1s,
    float* __restrict__ sp1) {
  int q = blockIdx.x >> 1;                 // 0..195
  int b = ((blockIdx.x & 1) << 8) + threadIdx.x;
  int qy = q / 14, qx = q % 14;

  float acc[4][20];
#pragma unroll
  for (int s = 0; s < 4; ++s)
#pragma unroll
    for (int oc = 0; oc < 20; ++oc) acc[s][oc] = 0.f;

#pragma unroll
  for (int s = 0; s < 4; ++s) {
    int y = 2 * qy + (s >> 1);
    int x = 2 * qx + (s & 1);
#pragma unroll
    for (int ky = 0; ky < 5; ++ky) {
      int iy = y + ky - 2;
      if (iy < 0 || iy >= 28) continue;    // block-uniform
#pragma unroll
      for (int kx = 0; kx < 5; ++kx) {
        int ix = x + kx - 2;
        if (ix < 0 || ix >= 28) continue;  // block-uniform
        float v = pois_t[(iy * 28 + ix) * 512 + b];
#pragma unroll
        for (int oc = 0; oc < 20; ++oc)
          acc[s][oc] += w1[oc * 25 + ky * 5 + kx] * v;
      }
    }
  }

#pragma unroll
  for (int oc = 0; oc < 20; ++oc) {
    float s4[4];
#pragma unroll
    for (int s = 0; s < 4; ++s) {
      int y = 2 * qy + (s >> 1);
      int x = 2 * qx + (s & 1);
      int idx = (oc * 784 + y * 28 + x) * 512 + b;
      float m = m1[idx] + acc[s][oc];
      float sp = 0.f;
      if (m > 1.0f) { sp = 1.f; m = 0.f; }
      m1[idx] = m;
      s4[s] = sp;
    }
    float a = 0.25f * (((s4[0] + s4[1]) + s4[2]) + s4[3]);
    int pidx = (oc * 196 + q) * 512 + b;
    float mm = m1s[pidx] + a;
    float spp = 0.f;
    if (mm > 0.75f) { spp = 1.f; mm = 0.f; }
    m1s[pidx] = mm;
    sp1[pidx] = spp;
  }
}

// ---------------------------------------------------------------------------
// 2x2 avgpool + IF fire, batch-innermost (layer 2 only now).
// ---------------------------------------------------------------------------
__global__ void pool_fire_t(const float* __restrict__ sin,
                            float* __restrict__ ms, float* __restrict__ sout,
                            int n, int H, float th) {
  int t = blockIdx.x * blockDim.x + threadIdx.x;
  if (t >= n) return;
  int b = t & 511;
  int r = t >> 9;
  int Ho = H >> 1;
  int pp = Ho * Ho;
  int c = r / pp, q = r % pp;
  int yo = q / Ho, xo = q % Ho;
  int ibase = (c * H * H + 2 * yo * H + 2 * xo) * 512 + b;
  float a = 0.25f * (sin[ibase] + sin[ibase + 512] +
                     sin[ibase + H * 512] + sin[ibase + H * 512 + 512]);
  float m = ms[t] + a;
  float sp = 0.f;
  if (m > th) { sp = 1.f; m = 0.f; }
  ms[t] = m;
  sout[t] = sp;
}

// ---------------------------------------------------------------------------
// w2 transpose: wT[q*50 + oc] = w2[oc*500 + q]
// ---------------------------------------------------------------------------
__global__ void transpose_w2(const float* __restrict__ w2,
                             float* __restrict__ wT) {
  int i = blockIdx.x * blockDim.x + threadIdx.x;
  if (i >= 25000) return;
  int oc = i / 500, q = i % 500;
  wT[q * 50 + oc] = w2[i];
}

// ---------------------------------------------------------------------------
// conv2 (20->50, 5x5, pad 2, 14x14) + IF fire. Lane = batch, acc[50] regs.
// Sum order (ic,ky,kx) ascending — bitwise identical.
// ---------------------------------------------------------------------------
__global__ __launch_bounds__(256) void conv2_fire_t(
    const float* __restrict__ sp1, const float* __restrict__ wT,
    float* __restrict__ m2, float* __restrict__ s2) {
  int p = blockIdx.x >> 1;
  int b = ((blockIdx.x & 1) << 8) + threadIdx.x;
  int y = p / 14, x = p % 14;
  float acc[50];
#pragma unroll
  for (int oc = 0; oc < 50; ++oc) acc[oc] = 0.f;
  for (int ic = 0; ic < 20; ++ic) {
#pragma unroll
    for (int ky = 0; ky < 5; ++ky) {
      int iy = y + ky - 2;
      if (iy < 0 || iy >= 14) continue;
#pragma unroll
      for (int kx = 0; kx < 5; ++kx) {
        int ix = x + kx - 2;
        if (ix < 0 || ix >= 14) continue;
        float v = sp1[(ic * 196 + iy * 14 + ix) * 512 + b];
        const float* wrow = wT + (ic * 25 + ky * 5 + kx) * 50;
#pragma unroll
        for (int oc = 0; oc < 50; ++oc)
          acc[oc] += wrow[oc] * v;
      }
    }
  }
#pragma unroll
  for (int oc = 0; oc < 50; ++oc) {
    int idx = (oc * 196 + p) * 512 + b;
    float m = m2[idx] + acc[oc];
    float sp = 0.f;
    if (m > 1.0f) { sp = 1.f; m = 0.f; }
    m2[idx] = m;
    s2[idx] = sp;
  }
}

// ---------------------------------------------------------------------------
// fc0 (2450->200) + IF fire + Tf0 accumulate. 1 n per thread, 400 blocks.
// k ascending, unroll-10 with batched loads (10 outstanding) — bit-identical.
// ---------------------------------------------------------------------------
__global__ __launch_bounds__(256) void fc0_fire_t(
    const float* __restrict__ sp2, const float* __restrict__ wf0,
    float* __restrict__ mf0, float* __restrict__ Tf0) {
  int n = blockIdx.x >> 1;                       // 0..199
  int b = ((blockIdx.x & 1) << 8) + threadIdx.x; // 0..511
  const float* w0 = wf0 + n * 2450;
  float acc = 0.f;
  for (int k0 = 0; k0 < 2450; k0 += 10) {        // 2450 = 245*10 exact
    float v[10];
#pragma unroll
    for (int u = 0; u < 10; ++u) v[u] = sp2[(k0 + u) * 512 + b];
#pragma unroll
    for (int u = 0; u < 10; ++u) acc += w0[k0 + u] * v[u];
  }
  int idx = n * 512 + b;
  float m = mf0[idx] + acc;
  float sp = 0.f;
  if (m > 1.0f) { sp = 1.f; m = 0.f; }
  mf0[idx] = m;
  Tf0[idx] += sp;
}

// ---------------------------------------------------------------------------
// final: out[b][i] = (Tf0_t[.][b] . wf1[i]) / 1 / 100
// ---------------------------------------------------------------------------
__global__ void fc1_out_t(const float* __restrict__ Tf0,
                          const float* __restrict__ wf1,
                          float* __restrict__ out) {
  int idx = blockIdx.x * blockDim.x + threadIdx.x;
  if (idx >= BATCH * 10) return;
  int b = idx / 10, i = idx % 10;
  float a = 0.f;
  for (int j = 0; j < 200; ++j) a += Tf0[j * 512 + b] * wf1[i * 200 + j];
  out[idx] = (a / 1.0f) / 100.0f;
}

// ---------------------------------------------------------------------------
extern "C" void kernel_launch(void* const* d_in, const int* in_sizes, int n_in,
                              void* d_out, int out_size, void* d_ws, size_t ws_size,
                              hipStream_t stream) {
  (void)in_sizes; (void)n_in; (void)out_size; (void)ws_size;
  const float* x   = (const float*)d_in[0];
  const float* w1  = (const float*)d_in[1];
  const float* w2  = (const float*)d_in[2];
  const float* wf0 = (const float*)d_in[3];
  const float* wf1 = (const float*)d_in[4];
  float* out = (float*)d_out;
  float* ws  = (float*)d_ws;

  // state (zeroed once per launch), all batch-innermost
  float* m1   = ws;                 // [20*784][512]  = 8,028,160
  float* m1s  = m1   + 8028160;     // [20*196][512]  = 2,007,040
  float* m2   = m1s  + 2007040;     // [50*196][512]  = 5,017,600
  float* m2s  = m2   + 5017600;     // [50*49][512]   = 1,254,400
  float* mf0  = m2s  + 1254400;     // [200][512]     =   102,400
  float* Tf0  = mf0  + 102400;      //                =   102,400
  const size_t state_f = 8028160 + 2007040 + 5017600 + 1254400 + 102400 + 102400;
  // transients
  float* pois = Tf0  + 102400;      // [784][512]     =   401,408
  float* sp1  = pois + 401408;      // [20*196][512]  = 2,007,040
  float* s2   = sp1  + 2007040;     // [50*196][512]  = 5,017,600
  float* sp2  = s2   + 5017600;     // [50*49][512]   = 1,254,400
  float* wT   = sp2  + 1254400;     // [500][50]      =    25,000
  uint32_t* keybuf = (uint32_t*)(wT + 25000);  // 200 u32

  hipMemsetAsync(ws, 0, state_f * sizeof(float), stream);

  keys_kernel<<<1, 128, 0, stream>>>(keybuf);
  transpose_w2<<<(25000 + 255) / 256, 256, 0, stream>>>(w2, wT);

  for (int s = 0; s < STEPS; ++s) {
    poisson_t<<<(NIN + 255) / 256, 256, 0, stream>>>(x, keybuf, s, pois);
    conv1_pool1_fused<<<196 * 2, 256, 0, stream>>>(pois, w1, m1, m1s, sp1);
    conv2_fire_t<<<196 * 2, 256, 0, stream>>>(sp1, wT, m2, s2);
    pool_fire_t<<<(1254400 + 255) / 256, 256, 0, stream>>>(s2, m2s, sp2,
                                                           1254400, 14, 0.75f);
    fc0_fire_t<<<400, 256, 0, stream>>>(sp2, wf0, mf0, Tf0);
  }
  fc1_out_t<<<(BATCH * 10 + 255) / 256, 256, 0, stream>>>(Tf0, wf1, out);
}